// Round 7
// baseline (67.425 us; speedup 1.0000x reference)
//
#include <hip/hip_runtime.h>
#include <hip/hip_bf16.h>

#define DD 128
#define NTC 8           // number of 128-col tiles (C=1000 -> Cpad=1024)

typedef __attribute__((ext_vector_type(8))) short short8;
typedef __attribute__((ext_vector_type(4))) float f32x4;

__device__ __forceinline__ unsigned pack2(float a, float b) {
    __hip_bfloat162 h = __float22bfloat162_rn(make_float2(a, b));  // v_cvt_pk_bf16_f32
    unsigned u;
    __builtin_memcpy(&u, &h, 4);
    return u;
}

// ---------- prep: centers -> bf16 tiles in ws (col-contiguous, NO swizzle) + csq_half ----------
// 8 threads per col: (col, q=dim-quarter, jh=half). Pad cols: 0 / 1e30.
// Layout: tile nt base = nt*32768; col r: 256 B at base + r*256; dim d at byte 2d.
__global__ void prep_centers(const float* __restrict__ ctr,
                             unsigned char* __restrict__ wsB,
                             float* __restrict__ csqh,
                             int C, int Cpad) {
    int gid = blockIdx.x * 256 + threadIdx.x;
    int col = gid >> 3, q = (gid >> 1) & 3, jh = gid & 1;
    if (col >= Cpad) return;
    const float* src = ctr + (size_t)col * DD + q * 32;
    const int r = col & 127;
    const unsigned base = (unsigned)(col >> 7) * 32768u + (unsigned)r * 256u;
    float cs = 0.f;
    #pragma unroll
    for (int jj = 0; jj < 2; ++jj) {
        int j = jh * 2 + jj;
        float4 v0 = make_float4(0.f,0.f,0.f,0.f), v1 = v0;
        if (col < C) {
            v0 = *(const float4*)(src + j * 8);
            v1 = *(const float4*)(src + j * 8 + 4);
        }
        cs = fmaf(v0.x,v0.x,cs); cs = fmaf(v0.y,v0.y,cs);
        cs = fmaf(v0.z,v0.z,cs); cs = fmaf(v0.w,v0.w,cs);
        cs = fmaf(v1.x,v1.x,cs); cs = fmaf(v1.y,v1.y,cs);
        cs = fmaf(v1.z,v1.z,cs); cs = fmaf(v1.w,v1.w,cs);
        uint4 w;
        w.x = pack2(v0.x, v0.y); w.y = pack2(v0.z, v0.w);
        w.z = pack2(v1.x, v1.y); w.w = pack2(v1.z, v1.w);
        *(uint4*)(wsB + base + ((unsigned)q * 4u + j) * 16u) = w;
    }
    cs += __shfl_xor(cs, 1); cs += __shfl_xor(cs, 2); cs += __shfl_xor(cs, 4);
    if ((gid & 7) == 0) csqh[col] = (col < C) ? 0.5f * cs : 1e30f;
}

// ---------- main: 64 rows/block x 1024 cols; barrier-free K-loop, B direct from L2 ----------
__global__ __launch_bounds__(256, 2) void center_mfma(
    const float* __restrict__ emb, const int* __restrict__ tgt,
    const float* __restrict__ ctr, const unsigned char* __restrict__ wsB,
    const float* __restrict__ csqh, float* __restrict__ partials)
{
    __shared__ uint4 sA4[1024];    // 64 rows x 256 B (bf16, XOR-swizzled) — A only
    __shared__ float sRT[64];
    __shared__ float sRed[4];
    unsigned char* sAb = (unsigned char*)sA4;

    const int t = threadIdx.x;
    const int row0 = blockIdx.x * 64;

    // ---- stage A (fp32 -> bf16 swizzled LDS) + per-row rt_half ----
    {
        const int r = t >> 2, q = t & 3;
        const float* srcE = emb + (size_t)(row0 + r) * DD + q * 32;
        const int y = tgt[row0 + r];
        const float* srcC = ctr + (size_t)y * DD + q * 32;
        float se = 0.f, sd = 0.f;
        #pragma unroll
        for (int j = 0; j < 4; ++j) {
            float4 e0 = *(const float4*)(srcE + j * 8);
            float4 e1 = *(const float4*)(srcE + j * 8 + 4);
            float4 c0 = *(const float4*)(srcC + j * 8);
            float4 c1 = *(const float4*)(srcC + j * 8 + 4);
            se = fmaf(e0.x,e0.x,se); se = fmaf(e0.y,e0.y,se);
            se = fmaf(e0.z,e0.z,se); se = fmaf(e0.w,e0.w,se);
            se = fmaf(e1.x,e1.x,se); se = fmaf(e1.y,e1.y,se);
            se = fmaf(e1.z,e1.z,se); se = fmaf(e1.w,e1.w,se);
            float d;
            d = e0.x-c0.x; sd = fmaf(d,d,sd);  d = e0.y-c0.y; sd = fmaf(d,d,sd);
            d = e0.z-c0.z; sd = fmaf(d,d,sd);  d = e0.w-c0.w; sd = fmaf(d,d,sd);
            d = e1.x-c1.x; sd = fmaf(d,d,sd);  d = e1.y-c1.y; sd = fmaf(d,d,sd);
            d = e1.z-c1.z; sd = fmaf(d,d,sd);  d = e1.w-c1.w; sd = fmaf(d,d,sd);
            uint4 wv;
            wv.x = pack2(e0.x, e0.y); wv.y = pack2(e0.z, e0.w);
            wv.z = pack2(e1.x, e1.y); wv.w = pack2(e1.z, e1.w);
            unsigned off = (unsigned)r * 256u +
                ((((unsigned)q * 4u + j) * 16u) ^ (((unsigned)r & 7u) << 4));
            *(uint4*)(sAb + off) = wv;
        }
        se += __shfl_xor(se, 1); se += __shfl_xor(se, 2);
        sd += __shfl_xor(sd, 1); sd += __shfl_xor(sd, 2);
        if (q == 0) sRT[r] = 0.5f * (1.0f + sd - se);
    }
    __syncthreads();

    const int l  = t & 63;
    const int w  = t >> 6;        // wave id: owns cols w*32..w*32+31 of each tile
    const int li = l & 15;
    const int lh = l >> 4;        // 0..3
    const unsigned swz = ((unsigned)li & 7u) << 4;

    // hoist A fragments (reused across all col tiles): k = 8*lh + 32*ks + e
    short8 aF[4][4];
    #pragma unroll
    for (int mf = 0; mf < 4; ++mf)
        #pragma unroll
        for (int ks = 0; ks < 4; ++ks)
            aF[mf][ks] = *(const short8*)(sAb + (unsigned)(li + 16*mf) * 256u +
                                          (((unsigned)(16*lh + 64*ks)) ^ swz));
    float rtv[16];
    #pragma unroll
    for (int mf = 0; mf < 4; ++mf)
        #pragma unroll
        for (int rr = 0; rr < 4; ++rr)
            rtv[mf*4+rr] = sRT[16*mf + 4*lh + rr];

    // per-lane base into ws: this lane's col0 fragment bytes (k-slice lh)
    const unsigned char* gBase = wsB + (unsigned)(w*32 + li) * 256u + (unsigned)lh * 16u;

    float tsum = 0.f;

    #pragma unroll
    for (int nt = 0; nt < NTC; ++nt) {
        const float cq0 = csqh[nt*128 + w*32 + li];
        const float cq1 = csqh[nt*128 + w*32 + 16 + li];

        // B fragments straight from L2-resident ws (16 B aligned short8 each)
        const unsigned char* g = gBase + (unsigned)nt * 32768u;
        short8 bF0[4], bF1[4];
        #pragma unroll
        for (int ks = 0; ks < 4; ++ks) {
            bF0[ks] = *(const short8*)(g + ks * 64u);            // col w*32+li
            bF1[ks] = *(const short8*)(g + 4096u + ks * 64u);    // col w*32+16+li
        }

        // C-init: 0.5*(1 + dis_intra - e_sq) - 0.5*c_sq  (pad cols -> -1e30)
        f32x4 acc[4][2];
        #pragma unroll
        for (int mf = 0; mf < 4; ++mf)
            #pragma unroll
            for (int rr = 0; rr < 4; ++rr) {
                acc[mf][0][rr] = rtv[mf*4+rr] - cq0;
                acc[mf][1][rr] = rtv[mf*4+rr] - cq1;
            }

        #pragma unroll
        for (int ks = 0; ks < 4; ++ks)
            #pragma unroll
            for (int mf = 0; mf < 4; ++mf) {
                acc[mf][0] = __builtin_amdgcn_mfma_f32_16x16x32_bf16(aF[mf][ks], bF0[ks], acc[mf][0], 0, 0, 0);
                acc[mf][1] = __builtin_amdgcn_mfma_f32_16x16x32_bf16(aF[mf][ks], bF1[ks], acc[mf][1], 0, 0, 0);
            }

        // epilogue: sum += 2*relu(acc)
        float s0 = 0.f, s1 = 0.f;
        #pragma unroll
        for (int mf = 0; mf < 4; ++mf)
            #pragma unroll
            for (int rr = 0; rr < 4; ++rr) {
                s0 = fmaf(2.0f, fmaxf(acc[mf][0][rr], 0.f), s0);
                s1 = fmaf(2.0f, fmaxf(acc[mf][1][rr], 0.f), s1);
            }
        tsum += s0 + s1;
    }

    // ---- block reduction -> deterministic per-block partial ----
    float s = tsum;
    #pragma unroll
    for (int off = 32; off; off >>= 1) s += __shfl_down(s, off);
    if (l == 0) sRed[w] = s;
    __syncthreads();
    if (t == 0) partials[blockIdx.x] = sRed[0] + sRed[1] + sRed[2] + sRed[3];
}

// ---------- final reduction ----------
__global__ void reduce_k(const float* __restrict__ partials, int n,
                         float* __restrict__ out, double diagSub, double invDenom) {
    __shared__ double sRed[4];
    int t = threadIdx.x;
    double s = 0.0;
    for (int i = t; i < n; i += 256) s += (double)partials[i];
    #pragma unroll
    for (int off = 32; off; off >>= 1) s += __shfl_down(s, off);
    if ((t & 63) == 0) sRed[t >> 6] = s;
    __syncthreads();
    if (t == 0) out[0] = (float)(((sRed[0]+sRed[1]+sRed[2]+sRed[3]) - diagSub) * invDenom);
}

extern "C" void kernel_launch(void* const* d_in, const int* in_sizes, int n_in,
                              void* d_out, int out_size, void* d_ws, size_t ws_size,
                              hipStream_t stream) {
    const float* emb = (const float*)d_in[0];
    const int*   tgt = (const int*)d_in[1];
    const float* ctr = (const float*)d_in[2];

    const int B = in_sizes[1];                 // 32768
    const int C = in_sizes[2] / DD;            // 1000
    const int Cpad = NTC * 128;                // 1024
    const int nblk = B / 64;                   // 512

    unsigned char* wsB = (unsigned char*)d_ws;                       // NTC*32 KB
    float* csqh = (float*)(wsB + (size_t)NTC * 32768);               // [Cpad]
    float* partials = csqh + Cpad;                                   // [nblk]

    prep_centers<<<(Cpad * 8) / 256, 256, 0, stream>>>(ctr, wsB, csqh, C, Cpad);
    center_mfma<<<nblk, 256, 0, stream>>>(emb, tgt, ctr, wsB, csqh, partials);
    reduce_k<<<1, 256, 0, stream>>>(partials, nblk, (float*)d_out,
                                    (double)B,
                                    1.0 / ((double)B * (double)(C - 1)));
}

// Round 8
// 29.567 us; speedup vs baseline: 2.2804x; 2.2804x over previous
//
#include <hip/hip_runtime.h>
#include <hip/hip_bf16.h>

#define DD 128
#define NTC 8           // number of 128-col tiles (C=1000 -> Cpad=1024)
#define BM 128          // rows per block

typedef __attribute__((ext_vector_type(8))) short short8;
typedef __attribute__((ext_vector_type(4))) float f32x4;

typedef __attribute__((address_space(1))) const void gvoid_t;
typedef __attribute__((address_space(3))) void svoid_t;
#define GLOAD_LDS16(g, s) __builtin_amdgcn_global_load_lds((gvoid_t*)(g), (svoid_t*)(s), 16, 0, 0)

__device__ __forceinline__ unsigned pack2(float a, float b) {
    __hip_bfloat162 h = __float22bfloat162_rn(make_float2(a, b));  // v_cvt_pk_bf16_f32
    unsigned u;
    __builtin_memcpy(&u, &h, 4);
    return u;
}

// ---------- prep: centers -> XOR-swizzled bf16 tiles in ws + csq_half ----------
// (rule #21: pre-swizzled global source + linear global_load_lds + swizzled ds_read)
__global__ void prep_centers(const float* __restrict__ ctr,
                             unsigned char* __restrict__ wsB,
                             float* __restrict__ csqh,
                             int C, int Cpad) {
    int gid = blockIdx.x * 256 + threadIdx.x;
    int col = gid >> 3, q = (gid >> 1) & 3, jh = gid & 1;
    if (col >= Cpad) return;
    const float* src = ctr + (size_t)col * DD + q * 32;
    const int r = col & 127;
    const unsigned base = (unsigned)(col >> 7) * 32768u + (unsigned)r * 256u;
    const unsigned sw = ((unsigned)r & 7u) << 4;
    float cs = 0.f;
    #pragma unroll
    for (int jj = 0; jj < 2; ++jj) {
        int j = jh * 2 + jj;
        float4 v0 = make_float4(0.f,0.f,0.f,0.f), v1 = v0;
        if (col < C) {
            v0 = *(const float4*)(src + j * 8);
            v1 = *(const float4*)(src + j * 8 + 4);
        }
        cs = fmaf(v0.x,v0.x,cs); cs = fmaf(v0.y,v0.y,cs);
        cs = fmaf(v0.z,v0.z,cs); cs = fmaf(v0.w,v0.w,cs);
        cs = fmaf(v1.x,v1.x,cs); cs = fmaf(v1.y,v1.y,cs);
        cs = fmaf(v1.z,v1.z,cs); cs = fmaf(v1.w,v1.w,cs);
        uint4 w;
        w.x = pack2(v0.x, v0.y); w.y = pack2(v0.z, v0.w);
        w.z = pack2(v1.x, v1.y); w.w = pack2(v1.z, v1.w);
        *(uint4*)(wsB + base + ((((unsigned)q * 4u + j) * 16u) ^ sw)) = w;
    }
    cs += __shfl_xor(cs, 1); cs += __shfl_xor(cs, 2); cs += __shfl_xor(cs, 4);
    if ((gid & 7) == 0) csqh[col] = (col < C) ? 0.5f * cs : 1e30f;
}

// ---------- main: 128 rows/block x 1024 cols; 8 waves; B double-buffered, 1 barrier/tile ----------
__global__ __launch_bounds__(512, 1) void center_mfma(
    const float* __restrict__ emb, const int* __restrict__ tgt,
    const float* __restrict__ ctr, const unsigned char* __restrict__ wsB,
    const float* __restrict__ csqh, float* __restrict__ partials)
{
    __shared__ uint4 sA4[2048];      // 128 rows x 256 B (bf16, XOR-swizzled)
    __shared__ uint4 sB4[4096];      // 2 x 32 KB double buffer
    __shared__ float sRT[BM];
    __shared__ float sRed[8];
    unsigned char* sAb = (unsigned char*)sA4;
    unsigned char* sB0 = (unsigned char*)sB4;
    unsigned char* sB1 = sB0 + 32768;

    const int t = threadIdx.x;
    const int row0 = blockIdx.x * BM;

    // ---- issue B stage(0) FIRST: overlaps with entire A-phase ----
    #pragma unroll
    for (int i = 0; i < 4; ++i) {
        unsigned off = (unsigned)(i * 512 + t) * 16u;
        GLOAD_LDS16(wsB + off, sB0 + off);
    }

    // ---- stage A (fp32 -> bf16 swizzled LDS) + per-row rt_half ----
    {
        const int r = t >> 2, q = t & 3;       // r in 0..127
        const float* srcE = emb + (size_t)(row0 + r) * DD + q * 32;
        const int y = tgt[row0 + r];
        const float* srcC = ctr + (size_t)y * DD + q * 32;
        float se = 0.f, sd = 0.f;
        #pragma unroll
        for (int j = 0; j < 4; ++j) {
            float4 e0 = *(const float4*)(srcE + j * 8);
            float4 e1 = *(const float4*)(srcE + j * 8 + 4);
            float4 c0 = *(const float4*)(srcC + j * 8);
            float4 c1 = *(const float4*)(srcC + j * 8 + 4);
            se = fmaf(e0.x,e0.x,se); se = fmaf(e0.y,e0.y,se);
            se = fmaf(e0.z,e0.z,se); se = fmaf(e0.w,e0.w,se);
            se = fmaf(e1.x,e1.x,se); se = fmaf(e1.y,e1.y,se);
            se = fmaf(e1.z,e1.z,se); se = fmaf(e1.w,e1.w,se);
            float d;
            d = e0.x-c0.x; sd = fmaf(d,d,sd);  d = e0.y-c0.y; sd = fmaf(d,d,sd);
            d = e0.z-c0.z; sd = fmaf(d,d,sd);  d = e0.w-c0.w; sd = fmaf(d,d,sd);
            d = e1.x-c1.x; sd = fmaf(d,d,sd);  d = e1.y-c1.y; sd = fmaf(d,d,sd);
            d = e1.z-c1.z; sd = fmaf(d,d,sd);  d = e1.w-c1.w; sd = fmaf(d,d,sd);
            uint4 wv;
            wv.x = pack2(e0.x, e0.y); wv.y = pack2(e0.z, e0.w);
            wv.z = pack2(e1.x, e1.y); wv.w = pack2(e1.z, e1.w);
            unsigned off = (unsigned)r * 256u +
                ((((unsigned)q * 4u + j) * 16u) ^ (((unsigned)r & 7u) << 4));
            *(uint4*)(sAb + off) = wv;
        }
        se += __shfl_xor(se, 1); se += __shfl_xor(se, 2);
        sd += __shfl_xor(sd, 1); sd += __shfl_xor(sd, 2);
        if (q == 0) sRT[r] = 0.5f * (1.0f + sd - se);
    }
    __syncthreads();   // A + stage(0) complete

    const int l  = t & 63;
    const int w  = t >> 6;        // 0..7
    const int wr = w >> 2;        // row-half: rows wr*64 .. +63
    const int wc = w & 3;         // col-quarter: cols wc*32 .. +31 of each tile
    const int li = l & 15;
    const int lh = l >> 4;        // 0..3
    const unsigned swz = ((unsigned)li & 7u) << 4;

    // hoist A fragments: row = wr*64 + 16*mf + li (row&7 == li&7), k = 8*lh + 32*ks + e
    short8 aF[4][4];
    #pragma unroll
    for (int mf = 0; mf < 4; ++mf)
        #pragma unroll
        for (int ks = 0; ks < 4; ++ks)
            aF[mf][ks] = *(const short8*)(sAb + (unsigned)(wr*64 + 16*mf + li) * 256u +
                                          (((unsigned)(16*lh + 64*ks)) ^ swz));
    float rtv[16];
    #pragma unroll
    for (int mf = 0; mf < 4; ++mf)
        #pragma unroll
        for (int rr = 0; rr < 4; ++rr)
            rtv[mf*4+rr] = sRT[wr*64 + 16*mf + 4*lh + rr];

    float tsum = 0.f;

    #pragma unroll
    for (int nt = 0; nt < NTC; ++nt) {
        unsigned char* bufR = (nt & 1) ? sB1 : sB0;
        unsigned char* bufW = (nt & 1) ? sB0 : sB1;

        __syncthreads();   // stage(nt) landed (vmcnt(0) drain); bufW reads all done

        // csq loads FIRST (oldest vmem) -> consumed at vmcnt(4), stages stay in flight
        const float cq0 = csqh[nt*128 + wc*32 + li];
        const float cq1 = csqh[nt*128 + wc*32 + 16 + li];

        if (nt + 1 < NTC) {   // stage next tile into idle buffer; covered by this phase
            const unsigned char* g = wsB + (size_t)(nt + 1) * 32768;
            #pragma unroll
            for (int i = 0; i < 4; ++i) {
                unsigned off = (unsigned)(i * 512 + t) * 16u;
                GLOAD_LDS16(g + off, bufW + off);
            }
        }

        // B fragments of tile nt from bufR (swizzled ds_read_b128)
        short8 bF0[4], bF1[4];
        #pragma unroll
        for (int ks = 0; ks < 4; ++ks) {
            unsigned kof = ((unsigned)(16*lh + 64*ks)) ^ swz;
            bF0[ks] = *(const short8*)(bufR + (unsigned)(wc*32 + li) * 256u + kof);
            bF1[ks] = *(const short8*)(bufR + (unsigned)(wc*32 + 16 + li) * 256u + kof);
        }

        // C-init: 0.5*(1 + dis_intra - e_sq) - 0.5*c_sq  (pad cols -> -1e30)
        f32x4 acc[4][2];
        #pragma unroll
        for (int mf = 0; mf < 4; ++mf)
            #pragma unroll
            for (int rr = 0; rr < 4; ++rr) {
                acc[mf][0][rr] = rtv[mf*4+rr] - cq0;
                acc[mf][1][rr] = rtv[mf*4+rr] - cq1;
            }

        #pragma unroll
        for (int ks = 0; ks < 4; ++ks)
            #pragma unroll
            for (int mf = 0; mf < 4; ++mf) {
                acc[mf][0] = __builtin_amdgcn_mfma_f32_16x16x32_bf16(aF[mf][ks], bF0[ks], acc[mf][0], 0, 0, 0);
                acc[mf][1] = __builtin_amdgcn_mfma_f32_16x16x32_bf16(aF[mf][ks], bF1[ks], acc[mf][1], 0, 0, 0);
            }

        // epilogue: sum += 2*relu(acc)
        float s0 = 0.f, s1 = 0.f;
        #pragma unroll
        for (int mf = 0; mf < 4; ++mf)
            #pragma unroll
            for (int rr = 0; rr < 4; ++rr) {
                s0 = fmaf(2.0f, fmaxf(acc[mf][0][rr], 0.f), s0);
                s1 = fmaf(2.0f, fmaxf(acc[mf][1][rr], 0.f), s1);
            }
        tsum += s0 + s1;
    }

    // ---- block reduction -> deterministic per-block partial ----
    float s = tsum;
    #pragma unroll
    for (int off = 32; off; off >>= 1) s += __shfl_down(s, off);
    if (l == 0) sRed[w] = s;
    __syncthreads();
    if (t == 0) {
        float bs = 0.f;
        #pragma unroll
        for (int i = 0; i < 8; ++i) bs += sRed[i];
        partials[blockIdx.x] = bs;
    }
}

// ---------- final reduction ----------
__global__ void reduce_k(const float* __restrict__ partials, int n,
                         float* __restrict__ out, double diagSub, double invDenom) {
    __shared__ double sRed[4];
    int t = threadIdx.x;
    double s = 0.0;
    for (int i = t; i < n; i += 256) s += (double)partials[i];
    #pragma unroll
    for (int off = 32; off; off >>= 1) s += __shfl_down(s, off);
    if ((t & 63) == 0) sRed[t >> 6] = s;
    __syncthreads();
    if (t == 0) out[0] = (float)(((sRed[0]+sRed[1]+sRed[2]+sRed[3]) - diagSub) * invDenom);
}

extern "C" void kernel_launch(void* const* d_in, const int* in_sizes, int n_in,
                              void* d_out, int out_size, void* d_ws, size_t ws_size,
                              hipStream_t stream) {
    const float* emb = (const float*)d_in[0];
    const int*   tgt = (const int*)d_in[1];
    const float* ctr = (const float*)d_in[2];

    const int B = in_sizes[1];                 // 32768
    const int C = in_sizes[2] / DD;            // 1000
    const int Cpad = NTC * 128;                // 1024
    const int nblk = B / BM;                   // 256 = 1 block/CU

    unsigned char* wsB = (unsigned char*)d_ws;                       // NTC*32 KB
    float* csqh = (float*)(wsB + (size_t)NTC * 32768);               // [Cpad]
    float* partials = csqh + Cpad;                                   // [nblk]

    prep_centers<<<(Cpad * 8) / 256, 256, 0, stream>>>(ctr, wsB, csqh, C, Cpad);
    center_mfma<<<nblk, 512, 0, stream>>>(emb, tgt, ctr, wsB, csqh, partials);
    reduce_k<<<1, 256, 0, stream>>>(partials, nblk, (float*)d_out,
                                    (double)B,
                                    1.0 / ((double)B * (double)(C - 1)));
}

// Round 9
// 24.880 us; speedup vs baseline: 2.7100x; 1.1884x over previous
//
#include <hip/hip_runtime.h>

#define DD 128
#define NTC 8           // 8 col-tiles of 128 -> Cpad = 1024

typedef __attribute__((ext_vector_type(4))) float f32x4;
typedef long long i64;

typedef __attribute__((address_space(1))) const void gvoid_t;
typedef __attribute__((address_space(3))) void svoid_t;
#define GLOAD_LDS16(g, s) __builtin_amdgcn_global_load_lds((gvoid_t*)(g), (svoid_t*)(s), 16, 0, 0)

__device__ __forceinline__ unsigned pk8(float a, float b, float c, float d) {
    int v = __builtin_amdgcn_cvt_pk_fp8_f32(a, b, 0, false);   // bytes 0,1
    v = __builtin_amdgcn_cvt_pk_fp8_f32(c, d, v, true);        // bytes 2,3
    return (unsigned)v;
}

// ---------- prep: centers -> fp8 e4m3, swizzled, into ws + csq_half ----------
// 4 threads/col (col, q = 32-dim quarter). Pad cols: zeros / csq 1e30.
// Layout: tile nt base nt*16K; col r (0..127): 128 B at base + r*128;
// 8-B slot j at byte (8*j) ^ ((r&15)<<3).
__global__ void prep_centers(const float* __restrict__ ctr,
                             unsigned char* __restrict__ wsB,
                             float* __restrict__ csqh, int C, int Cpad) {
    int gid = blockIdx.x * 256 + threadIdx.x;
    int col = gid >> 2, q = gid & 3;
    if (col >= Cpad) return;
    const float* src = ctr + (size_t)col * DD + q * 32;
    const int r = col & 127;
    unsigned char* dst = wsB + (unsigned)(col >> 7) * 16384u + (unsigned)r * 128u;
    const unsigned sw = ((unsigned)r & 15u) << 3;
    float cs = 0.f;
    #pragma unroll
    for (int m = 0; m < 4; ++m) {
        float4 v0 = make_float4(0.f,0.f,0.f,0.f), v1 = v0;
        if (col < C) {
            v0 = *(const float4*)(src + m * 8);
            v1 = *(const float4*)(src + m * 8 + 4);
        }
        cs = fmaf(v0.x,v0.x,cs); cs = fmaf(v0.y,v0.y,cs);
        cs = fmaf(v0.z,v0.z,cs); cs = fmaf(v0.w,v0.w,cs);
        cs = fmaf(v1.x,v1.x,cs); cs = fmaf(v1.y,v1.y,cs);
        cs = fmaf(v1.z,v1.z,cs); cs = fmaf(v1.w,v1.w,cs);
        uint2 u;
        u.x = pk8(v0.x, v0.y, v0.z, v0.w);
        u.y = pk8(v1.x, v1.y, v1.z, v1.w);
        *(uint2*)(dst + ((((unsigned)(q * 4 + m)) * 8u) ^ sw)) = u;
    }
    cs += __shfl_xor(cs, 1); cs += __shfl_xor(cs, 2);
    if (q == 0) csqh[col] = (col < C) ? 0.5f * cs : 1e30f;
}

// ---------- main: 128 rows/block; FULL fp8 B resident in LDS; barrier-free K-loop ----------
__global__ __launch_bounds__(512, 1) void center_mfma(
    const float* __restrict__ emb, const int* __restrict__ tgt,
    const float* __restrict__ ctr, const unsigned char* __restrict__ wsB,
    const float* __restrict__ csqh, float* __restrict__ partials)
{
    __shared__ uint4 sB4[8192];   // 128 KB: all 1024 cols fp8, swizzled
    __shared__ uint4 sA4[1024];   // 16 KB: 128 rows fp8, swizzled
    __shared__ float sRT[128];
    __shared__ float sRed[8];
    unsigned char* sAb = (unsigned char*)sA4;
    const unsigned char* sBb = (const unsigned char*)sB4;

    const int t = threadIdx.x;
    const int row0 = blockIdx.x * 128;

    // ---- A-phase 1: issue ALL fp32 global loads to regs (oldest vmem) ----
    const int r = t >> 2, q = t & 3;
    const float* srcE = emb + (size_t)(row0 + r) * DD + q * 32;
    const int y = tgt[row0 + r];
    const float* srcC = ctr + (size_t)y * DD + q * 32;
    float4 ev[8], cv[8];
    #pragma unroll
    for (int m = 0; m < 8; ++m) ev[m] = *(const float4*)(srcE + m * 4);
    #pragma unroll
    for (int m = 0; m < 8; ++m) cv[m] = *(const float4*)(srcC + m * 4);

    // ---- B one-time load (younger vmem: stays in flight under A-compute) ----
    #pragma unroll
    for (int i = 0; i < 16; ++i) {
        unsigned off = (unsigned)(i * 512 + t) * 16u;
        GLOAD_LDS16(wsB + off, (unsigned char*)sB4 + off);
    }

    // ---- A-phase 2: rt_half + fp8 pack + swizzled LDS write ----
    {
        const unsigned swA = ((unsigned)r & 15u) << 3;
        float se = 0.f, sd = 0.f;
        #pragma unroll
        for (int m = 0; m < 4; ++m) {
            float4 e0 = ev[2*m], e1 = ev[2*m+1], c0 = cv[2*m], c1 = cv[2*m+1];
            se = fmaf(e0.x,e0.x,se); se = fmaf(e0.y,e0.y,se);
            se = fmaf(e0.z,e0.z,se); se = fmaf(e0.w,e0.w,se);
            se = fmaf(e1.x,e1.x,se); se = fmaf(e1.y,e1.y,se);
            se = fmaf(e1.z,e1.z,se); se = fmaf(e1.w,e1.w,se);
            float d;
            d = e0.x-c0.x; sd = fmaf(d,d,sd);  d = e0.y-c0.y; sd = fmaf(d,d,sd);
            d = e0.z-c0.z; sd = fmaf(d,d,sd);  d = e0.w-c0.w; sd = fmaf(d,d,sd);
            d = e1.x-c1.x; sd = fmaf(d,d,sd);  d = e1.y-c1.y; sd = fmaf(d,d,sd);
            d = e1.z-c1.z; sd = fmaf(d,d,sd);  d = e1.w-c1.w; sd = fmaf(d,d,sd);
            uint2 u;
            u.x = pk8(e0.x, e0.y, e0.z, e0.w);
            u.y = pk8(e1.x, e1.y, e1.z, e1.w);
            *(uint2*)(sAb + (unsigned)r * 128u +
                      ((((unsigned)(q * 4 + m)) * 8u) ^ swA)) = u;
        }
        se += __shfl_xor(se, 1); se += __shfl_xor(se, 2);
        sd += __shfl_xor(sd, 1); sd += __shfl_xor(sd, 2);
        if (q == 0) sRT[r] = 0.5f * (1.0f + sd - se);
    }
    __syncthreads();   // A LDS writes + full B load visible (single drain, once)

    const int l  = t & 63;
    const int w  = t >> 6;        // 0..7
    const int wr = w >> 2;        // row half (64 rows)
    const int wc = w & 3;         // col quarter (32 cols per tile)
    const int li = l & 15;
    const int lh = l >> 4;        // 0..3
    const unsigned sw = (unsigned)li << 3;   // (idx&15)<<3, idx%16 == li everywhere below

    // hoist A fragments: row = wr*64 + 16*mf + li; k = 8*lh + 32*ks + e
    i64 aF[4][4];
    #pragma unroll
    for (int mf = 0; mf < 4; ++mf)
        #pragma unroll
        for (int ks = 0; ks < 4; ++ks)
            aF[mf][ks] = *(const i64*)(sAb + (unsigned)(wr*64 + 16*mf + li) * 128u +
                                       (((unsigned)(8*lh + 32*ks)) ^ sw));
    float rtv[16];
    #pragma unroll
    for (int mf = 0; mf < 4; ++mf)
        #pragma unroll
        for (int rr = 0; rr < 4; ++rr)
            rtv[mf*4+rr] = sRT[wr*64 + 16*mf + 4*lh + rr];

    // hoist all csq (compile-time indexed via full unroll)
    float cqa[NTC], cqb[NTC];
    #pragma unroll
    for (int nt = 0; nt < NTC; ++nt) {
        cqa[nt] = csqh[nt*128 + wc*32 + li];
        cqb[nt] = csqh[nt*128 + wc*32 + 16 + li];
    }

    float tsum = 0.f;

    #pragma unroll
    for (int nt = 0; nt < NTC; ++nt) {
        // B fragments from resident LDS (no barriers, no vmem)
        i64 bF0[4], bF1[4];
        #pragma unroll
        for (int ks = 0; ks < 4; ++ks) {
            unsigned kof = ((unsigned)(8*lh + 32*ks)) ^ sw;
            bF0[ks] = *(const i64*)(sBb + (unsigned)nt*16384u +
                                    (unsigned)(wc*32 + li) * 128u + kof);
            bF1[ks] = *(const i64*)(sBb + (unsigned)nt*16384u +
                                    (unsigned)(wc*32 + 16 + li) * 128u + kof);
        }

        // C-init: 0.5*(1 + dis_intra - e_sq) - 0.5*c_sq  (pad cols -> -1e30)
        f32x4 acc[4][2];
        #pragma unroll
        for (int mf = 0; mf < 4; ++mf)
            #pragma unroll
            for (int rr = 0; rr < 4; ++rr) {
                acc[mf][0][rr] = rtv[mf*4+rr] - cqa[nt];
                acc[mf][1][rr] = rtv[mf*4+rr] - cqb[nt];
            }

        #pragma unroll
        for (int ks = 0; ks < 4; ++ks)
            #pragma unroll
            for (int mf = 0; mf < 4; ++mf) {
                acc[mf][0] = __builtin_amdgcn_mfma_f32_16x16x32_fp8_fp8(aF[mf][ks], bF0[ks], acc[mf][0], 0, 0, 0);
                acc[mf][1] = __builtin_amdgcn_mfma_f32_16x16x32_fp8_fp8(aF[mf][ks], bF1[ks], acc[mf][1], 0, 0, 0);
            }

        // epilogue: sum += 2*relu(acc)
        float s0 = 0.f, s1 = 0.f;
        #pragma unroll
        for (int mf = 0; mf < 4; ++mf)
            #pragma unroll
            for (int rr = 0; rr < 4; ++rr) {
                s0 = fmaf(2.0f, fmaxf(acc[mf][0][rr], 0.f), s0);
                s1 = fmaf(2.0f, fmaxf(acc[mf][1][rr], 0.f), s1);
            }
        tsum += s0 + s1;
    }

    // ---- block reduction -> deterministic per-block partial ----
    float s = tsum;
    #pragma unroll
    for (int off = 32; off; off >>= 1) s += __shfl_down(s, off);
    if (l == 0) sRed[w] = s;
    __syncthreads();
    if (t == 0) {
        float bs = 0.f;
        #pragma unroll
        for (int i = 0; i < 8; ++i) bs += sRed[i];
        partials[blockIdx.x] = bs;
    }
}

// ---------- final reduction ----------
__global__ void reduce_k(const float* __restrict__ partials, int n,
                         float* __restrict__ out, double diagSub, double invDenom) {
    __shared__ double sRed[4];
    int t = threadIdx.x;
    double s = 0.0;
    for (int i = t; i < n; i += 256) s += (double)partials[i];
    #pragma unroll
    for (int off = 32; off; off >>= 1) s += __shfl_down(s, off);
    if ((t & 63) == 0) sRed[t >> 6] = s;
    __syncthreads();
    if (t == 0) out[0] = (float)(((sRed[0]+sRed[1]+sRed[2]+sRed[3]) - diagSub) * invDenom);
}

extern "C" void kernel_launch(void* const* d_in, const int* in_sizes, int n_in,
                              void* d_out, int out_size, void* d_ws, size_t ws_size,
                              hipStream_t stream) {
    const float* emb = (const float*)d_in[0];
    const int*   tgt = (const int*)d_in[1];
    const float* ctr = (const float*)d_in[2];

    const int B = in_sizes[1];                 // 32768
    const int C = in_sizes[2] / DD;            // 1000
    const int Cpad = NTC * 128;                // 1024
    const int nblk = B / 128;                  // 256 = 1 block/CU

    unsigned char* wsB = (unsigned char*)d_ws;                       // NTC*16 KB fp8
    float* csqh = (float*)(wsB + (size_t)NTC * 16384);               // [Cpad]
    float* partials = csqh + Cpad;                                   // [nblk]

    prep_centers<<<(Cpad * 4) / 256, 256, 0, stream>>>(ctr, wsB, csqh, C, Cpad);
    center_mfma<<<nblk, 512, 0, stream>>>(emb, tgt, ctr, wsB, csqh, partials);
    reduce_k<<<1, 256, 0, stream>>>(partials, nblk, (float*)d_out,
                                    (double)B,
                                    1.0 / ((double)B * (double)(C - 1)));
}